// Round 4
// baseline (427.601 us; speedup 1.0000x reference)
//
#include <hip/hip_runtime.h>
#include <hip/hip_bf16.h>

#define BS   2
#define SEQ  2048
#define DIM  1024
#define HD   32
#define G    8
#define HPG  4
#define KVD  256
#define NTOT (DIM + 2*KVD)   // 1536 output cols of the fused QKV GEMM

typedef __attribute__((ext_vector_type(8))) _Float16 f16x8;
typedef __attribute__((ext_vector_type(4))) float f32x4;

__device__ __forceinline__ unsigned short f2h(float f) {
    _Float16 h = (_Float16)f;
    return __builtin_bit_cast(unsigned short, h);
}

// ---------------- fp32 -> fp16 convert (vectorized, grid-stride) ----------------
__global__ __launch_bounds__(256) void cvt_kernel(const float* __restrict__ in,
                                                  unsigned short* __restrict__ out, int n) {
    int nv = n >> 2;
    for (int i = blockIdx.x * blockDim.x + threadIdx.x; i < nv; i += gridDim.x * blockDim.x) {
        float4 v = reinterpret_cast<const float4*>(in)[i];
        ushort4 o;
        o.x = f2h(v.x); o.y = f2h(v.y); o.z = f2h(v.z); o.w = f2h(v.w);
        reinterpret_cast<ushort4*>(out)[i] = o;
    }
}

// ---------------- fused QKV projection GEMM ----------------
// Y[m][n] = sum_k X[m][k] * W[n][k],  M=4096, N=1536, K=1024
// block = 4 waves, tile 128x64; wave w owns rows {m0+w*16, m0+64+w*16}, 4 n-frags.
__global__ __launch_bounds__(256) void qkv_gemm(const unsigned short* __restrict__ xb,
                                                const unsigned short* __restrict__ wb,
                                                unsigned short* __restrict__ qb,
                                                unsigned short* __restrict__ kb,
                                                unsigned short* __restrict__ vtb) {
    int lane = threadIdx.x & 63;
    int w    = threadIdx.x >> 6;
    int m0   = blockIdx.y * 128 + w * 16;
    int n0   = blockIdx.x * 64;
    int lr = lane & 15, lq = lane >> 4;

    f32x4 acc[2][4] = {};
    const unsigned short* xrow0 = xb + (m0 + lr) * DIM + lq * 8;
    const unsigned short* xrow1 = xrow0 + 64 * DIM;
    for (int ks = 0; ks < DIM; ks += 32) {
        f16x8 a0 = *reinterpret_cast<const f16x8*>(xrow0 + ks);
        f16x8 a1 = *reinterpret_cast<const f16x8*>(xrow1 + ks);
        #pragma unroll
        for (int nf = 0; nf < 4; nf++) {
            const unsigned short* wrow = wb + (n0 + nf * 16 + lr) * DIM + ks + lq * 8;
            f16x8 bfr = *reinterpret_cast<const f16x8*>(wrow);
            acc[0][nf] = __builtin_amdgcn_mfma_f32_16x16x32_f16(a0, bfr, acc[0][nf], 0, 0, 0);
            acc[1][nf] = __builtin_amdgcn_mfma_f32_16x16x32_f16(a1, bfr, acc[1][nf], 0, 0, 0);
        }
    }
    #pragma unroll
    for (int mi = 0; mi < 2; mi++) {
        #pragma unroll
        for (int nf = 0; nf < 4; nf++) {
            int col = n0 + nf * 16 + lr;
            #pragma unroll
            for (int r = 0; r < 4; r++) {
                int row = m0 + mi * 64 + lq * 4 + r;
                unsigned short v = f2h(acc[mi][nf][r]);
                if (col < DIM) {
                    qb[row * DIM + col] = v;
                } else if (col < DIM + KVD) {
                    kb[row * KVD + (col - DIM)] = v;
                } else {
                    int b = row >> 11, s = row & 2047;
                    vtb[(b * KVD + (col - DIM - KVD)) * SEQ + s] = v;
                }
            }
        }
    }
}

// ---------------- flash-style GQA attention, swapped-QK^T, zero-shuffle PV ----------------
// block = one (b, g, 16-row q-tile); 4 waves = the 4 heads of the group. No LDS.
// Swapped: S^T = mfma(K, Q) -> lane (lq,lr) holds q-row lr, keys {4lq..4lq+3, 16+4lq..+3}.
// PV uses the SAME key permutation on both A (P, in-register) and B (V, two 8B loads),
// so no cross-lane repack is needed (contraction is permutation-invariant).
__global__ __launch_bounds__(256) void gqa_attn(const unsigned short* __restrict__ qb,
                                                const unsigned short* __restrict__ kb,
                                                const unsigned short* __restrict__ vtb,
                                                float* __restrict__ out) {
    int lane = threadIdx.x & 63;
    int w    = threadIdx.x >> 6;
    int bi   = blockIdx.x;
    int qt = bi & 127;            // SEQ/16 = 128 q-tiles
    int g  = (bi >> 7) & 7;
    int b  = bi >> 10;
    int q0 = qt * 16;
    int lr = lane & 15, lq = lane >> 4;

    // Q as B-operand: lane provides Q[q0+lr][d = lq*8+j]
    f16x8 qf = *reinterpret_cast<const f16x8*>(
        qb + (b * SEQ + q0 + lr) * DIM + (g * HPG + w) * HD + lq * 8);

    f32x4 O0 = {}, O1 = {};
    float m = -1e30f, l = 0.f;

    const unsigned short* kbase = kb + b * SEQ * KVD + g * HD;
    const unsigned short* vbase = vtb + (b * KVD + g * HD) * SEQ;

    for (int kt = 0; kt < SEQ; kt += 32) {
        // K as A-operand: lane provides K[kt(+16)+lr][d = lq*8+j]
        f16x8 kf0 = *reinterpret_cast<const f16x8*>(kbase + (kt + lr) * KVD + lq * 8);
        f16x8 kf1 = *reinterpret_cast<const f16x8*>(kbase + (kt + 16 + lr) * KVD + lq * 8);
        f32x4 z = {};
        // S^T: lane holds q = lr; s0[r] = key kt+lq*4+r, s1[r] = key kt+16+lq*4+r
        f32x4 s0 = __builtin_amdgcn_mfma_f32_16x16x32_f16(kf0, qf, z, 0, 0, 0);
        f32x4 s1 = __builtin_amdgcn_mfma_f32_16x16x32_f16(kf1, qf, z, 0, 0, 0);

        // row max over 32 keys: 7 local fmax + reduce across lanes {lr, lr+16, lr+32, lr+48}
        float tm = fmaxf(fmaxf(fmaxf(s0[0], s0[1]), fmaxf(s0[2], s0[3])),
                         fmaxf(fmaxf(s1[0], s1[1]), fmaxf(s1[2], s1[3])));
        tm = fmaxf(tm, __shfl_xor(tm, 16, 64));
        tm = fmaxf(tm, __shfl_xor(tm, 32, 64));

        bool noresc = __all(tm <= m);           // defer-max: wave-uniform skip
        float mn = noresc ? m : fmaxf(m, tm);
        float sc = __expf(m - mn);
        m = mn;

        float p0 = __expf(s0[0] - mn), p1 = __expf(s0[1] - mn);
        float p2 = __expf(s0[2] - mn), p3 = __expf(s0[3] - mn);
        float p4 = __expf(s1[0] - mn), p5 = __expf(s1[1] - mn);
        float p6 = __expf(s1[2] - mn), p7 = __expf(s1[3] - mn);
        float rs = ((p0 + p1) + (p2 + p3)) + ((p4 + p5) + (p6 + p7));
        rs += __shfl_xor(rs, 16, 64);
        rs += __shfl_xor(rs, 32, 64);
        l = l * sc + rs;

        // P A-frag, in-register (slot->key: j<4 -> kt+4lq+j ; j>=4 -> kt+16+4lq+(j-4))
        int pkA0 = __builtin_bit_cast(int, __builtin_amdgcn_cvt_pkrtz(p0, p1));
        int pkA1 = __builtin_bit_cast(int, __builtin_amdgcn_cvt_pkrtz(p2, p3));
        int pkB0 = __builtin_bit_cast(int, __builtin_amdgcn_cvt_pkrtz(p4, p5));
        int pkB1 = __builtin_bit_cast(int, __builtin_amdgcn_cvt_pkrtz(p6, p7));
        int4 pvi = {pkA0, pkA1, pkB0, pkB1};
        f16x8 pa = __builtin_bit_cast(f16x8, pvi);

        if (!noresc) {
            // O rows are q = lq*4+r; fetch sc for those rows from lane (lq*4+r) of own 16-group
            #pragma unroll
            for (int r = 0; r < 4; r++) {
                float scr = __shfl(sc, lq * 4 + r, 16);
                O0[r] *= scr;
                O1[r] *= scr;
            }
        }

        // V B-frag with the SAME key permutation: slot j -> V[kt+pi(j)][d], d = lr (+16)
        const unsigned short* vrow0 = vbase + lr * SEQ + kt + lq * 4;
        const unsigned short* vrow1 = vbase + (16 + lr) * SEQ + kt + lq * 4;
        uint2 a0 = *reinterpret_cast<const uint2*>(vrow0);
        uint2 a1 = *reinterpret_cast<const uint2*>(vrow0 + 16);
        uint2 b0 = *reinterpret_cast<const uint2*>(vrow1);
        uint2 b1 = *reinterpret_cast<const uint2*>(vrow1 + 16);
        int4 vi0 = {(int)a0.x, (int)a0.y, (int)a1.x, (int)a1.y};
        int4 vi1 = {(int)b0.x, (int)b0.y, (int)b1.x, (int)b1.y};
        f16x8 vf0 = __builtin_bit_cast(f16x8, vi0);
        f16x8 vf1 = __builtin_bit_cast(f16x8, vi1);

        O0 = __builtin_amdgcn_mfma_f32_16x16x32_f16(pa, vf0, O0, 0, 0, 0);
        O1 = __builtin_amdgcn_mfma_f32_16x16x32_f16(pa, vf1, O1, 0, 0, 0);
    }

    // epilogue: O rows q = lq*4+r, cols d = lr (+16); l lives at lane (q) of each 16-group
    float* obase = out + (size_t)(b * SEQ) * DIM + (g * HPG + w) * HD;
    #pragma unroll
    for (int r = 0; r < 4; r++) {
        float lrow = __shfl(l, lq * 4 + r, 16);
        float inv = 1.0f / lrow;
        int row = q0 + lq * 4 + r;
        obase[(size_t)row * DIM + lr]      = O0[r] * inv;
        obase[(size_t)row * DIM + 16 + lr] = O1[r] * inv;
    }
}

extern "C" void kernel_launch(void* const* d_in, const int* in_sizes, int n_in,
                              void* d_out, int out_size, void* d_ws, size_t ws_size,
                              hipStream_t stream) {
    const float* x  = (const float*)d_in[0];
    const float* wq = (const float*)d_in[1];
    const float* wk = (const float*)d_in[2];
    const float* wv = (const float*)d_in[3];
    float* out = (float*)d_out;

    unsigned short* ws  = (unsigned short*)d_ws;
    unsigned short* xb  = ws;                                  // 4096*1024
    unsigned short* wb  = xb + (size_t)BS * SEQ * DIM;         // 1536*1024
    unsigned short* qb  = wb + (size_t)NTOT * DIM;             // 4096*1024
    unsigned short* kb  = qb + (size_t)BS * SEQ * DIM;         // 4096*256
    unsigned short* vtb = kb + (size_t)BS * SEQ * KVD;         // 4096*256 (transposed)

    cvt_kernel<<<1024, 256, 0, stream>>>(x, xb, BS * SEQ * DIM);
    cvt_kernel<<<256,  256, 0, stream>>>(wq, wb, DIM * DIM);
    cvt_kernel<<<64,   256, 0, stream>>>(wk, wb + (size_t)DIM * DIM, KVD * DIM);
    cvt_kernel<<<64,   256, 0, stream>>>(wv, wb + (size_t)DIM * DIM + (size_t)KVD * DIM, KVD * DIM);

    qkv_gemm<<<dim3(NTOT / 64, BS * SEQ / 128), 256, 0, stream>>>(xb, wb, qb, kb, vtb);
    gqa_attn<<<BS * G * (SEQ / 16), 256, 0, stream>>>(qb, kb, vtb, out);
}

// Round 5
// 236.040 us; speedup vs baseline: 1.8116x; 1.8116x over previous
//
#include <hip/hip_runtime.h>
#include <hip/hip_bf16.h>

#define BS   2
#define SEQ  2048
#define DIM  1024
#define HD   32
#define G    8
#define HPG  4
#define KVD  256
#define NTOT (DIM + 2*KVD)   // 1536 output cols of the fused QKV GEMM

typedef __attribute__((ext_vector_type(8))) _Float16 f16x8;
typedef __attribute__((ext_vector_type(4))) float f32x4;

__device__ __forceinline__ unsigned short f2h(float f) {
    _Float16 h = (_Float16)f;
    return __builtin_bit_cast(unsigned short, h);
}

// ---------------- fp32 -> fp16 convert (vectorized, grid-stride) ----------------
__global__ __launch_bounds__(256) void cvt_kernel(const float* __restrict__ in,
                                                  unsigned short* __restrict__ out, int n) {
    int nv = n >> 2;
    for (int i = blockIdx.x * blockDim.x + threadIdx.x; i < nv; i += gridDim.x * blockDim.x) {
        float4 v = reinterpret_cast<const float4*>(in)[i];
        ushort4 o;
        o.x = f2h(v.x); o.y = f2h(v.y); o.z = f2h(v.z); o.w = f2h(v.w);
        reinterpret_cast<ushort4*>(out)[i] = o;
    }
}

// ---------------- fused QKV projection GEMM ----------------
// Y[m][n] = sum_k X[m][k] * W[n][k],  M=4096, N=1536, K=1024
// block = 4 waves, tile 128x64; wave w owns rows {m0+w*16, m0+64+w*16}, 4 n-frags.
__global__ __launch_bounds__(256) void qkv_gemm(const unsigned short* __restrict__ xb,
                                                const unsigned short* __restrict__ wb,
                                                unsigned short* __restrict__ qb,
                                                unsigned short* __restrict__ kb,
                                                unsigned short* __restrict__ vtb) {
    int lane = threadIdx.x & 63;
    int w    = threadIdx.x >> 6;
    int m0   = blockIdx.y * 128 + w * 16;
    int n0   = blockIdx.x * 64;
    int lr = lane & 15, lq = lane >> 4;

    f32x4 acc[2][4] = {};
    const unsigned short* xrow0 = xb + (m0 + lr) * DIM + lq * 8;
    const unsigned short* xrow1 = xrow0 + 64 * DIM;
    for (int ks = 0; ks < DIM; ks += 32) {
        f16x8 a0 = *reinterpret_cast<const f16x8*>(xrow0 + ks);
        f16x8 a1 = *reinterpret_cast<const f16x8*>(xrow1 + ks);
        #pragma unroll
        for (int nf = 0; nf < 4; nf++) {
            const unsigned short* wrow = wb + (n0 + nf * 16 + lr) * DIM + ks + lq * 8;
            f16x8 bfr = *reinterpret_cast<const f16x8*>(wrow);
            acc[0][nf] = __builtin_amdgcn_mfma_f32_16x16x32_f16(a0, bfr, acc[0][nf], 0, 0, 0);
            acc[1][nf] = __builtin_amdgcn_mfma_f32_16x16x32_f16(a1, bfr, acc[1][nf], 0, 0, 0);
        }
    }
    #pragma unroll
    for (int mi = 0; mi < 2; mi++) {
        #pragma unroll
        for (int nf = 0; nf < 4; nf++) {
            int col = n0 + nf * 16 + lr;
            #pragma unroll
            for (int r = 0; r < 4; r++) {
                int row = m0 + mi * 64 + lq * 4 + r;
                unsigned short v = f2h(acc[mi][nf][r]);
                if (col < DIM) {
                    qb[row * DIM + col] = v;
                } else if (col < DIM + KVD) {
                    kb[row * KVD + (col - DIM)] = v;
                } else {
                    int b = row >> 11, s = row & 2047;
                    vtb[(b * KVD + (col - DIM - KVD)) * SEQ + s] = v;
                }
            }
        }
    }
}

// ---------------- flash-style GQA attention ----------------
// block = one (b, g, 32-row q-tile); 4 waves = 4 heads sharing the group's K/V.
// K/V tiles (32 keys) double-buffered in LDS via global_load_lds(16B), 2-phase pipeline.
// Swapped QK^T (S^T = mfma(K,Q)): lane (lq,lr) holds q-row lr, keys {4lq..+3, 16+4lq..+3};
// softmax fully in-register; PV uses the same key permutation on P (in-reg) and V (LDS reads).
__global__ __launch_bounds__(256) void gqa_attn(const unsigned short* __restrict__ qb,
                                                const unsigned short* __restrict__ kb,
                                                const unsigned short* __restrict__ vtb,
                                                float* __restrict__ out) {
    __shared__ unsigned short Ks[2][32 * 32];   // [buf][key][32 dims], 64B rows
    __shared__ unsigned short Vs[2][32 * 32];   // [buf][d]  [32 keys], 64B rows

    int tid  = threadIdx.x;
    int lane = tid & 63;
    int w    = tid >> 6;
    int bi   = blockIdx.x;
    int qt = bi & 63;             // SEQ/32 = 64 q-tiles of 32 rows
    int g  = (bi >> 6) & 7;
    int b  = bi >> 9;
    int q0 = qt * 32;
    int lr = lane & 15, lq = lane >> 4;

    const unsigned short* kbase = kb + b * SEQ * KVD + g * HD;
    const unsigned short* vbase = vtb + (b * KVD + g * HD) * SEQ;

    // staging role: threads 0-127 stage K (16B chunks), 128-255 stage V
    bool isK = tid < 128;
    int ci   = isK ? tid : tid - 128;
    int srow = ci >> 2, sc4 = ci & 3;
    const unsigned short* sbase = isK ? (kbase + srow * KVD + sc4 * 8)
                                      : (vbase + srow * SEQ + sc4 * 8);
    int sstep = isK ? KVD : 1;                     // global advance per +1 key
    unsigned short* dbase = isK ? &Ks[0][ci * 8] : &Vs[0][ci * 8];

    // Q fragments (B-operand), pre-scaled by log2(e) so softmax uses native exp2
    f16x8 qf[2];
    #pragma unroll
    for (int t = 0; t < 2; t++) {
        qf[t] = *reinterpret_cast<const f16x8*>(
            qb + (b * SEQ + q0 + t * 16 + lr) * DIM + (g * HPG + w) * HD + lq * 8);
        qf[t] = qf[t] * (_Float16)1.44269504f;
    }

    f32x4 O[2][2] = {};
    float m[2] = {-1e30f, -1e30f}, l[2] = {0.f, 0.f};

    // prologue stage of tile 0
    __builtin_amdgcn_global_load_lds(
        (const __attribute__((address_space(1))) unsigned int*)(sbase),
        (__attribute__((address_space(3))) unsigned int*)(dbase), 16, 0, 0);
    __syncthreads();

    for (int kt = 0; kt < SEQ; kt += 32) {
        int cur = (kt >> 5) & 1;
        if (kt + 32 < SEQ) {       // issue next-tile stage; completes at this iter's barrier
            __builtin_amdgcn_global_load_lds(
                (const __attribute__((address_space(1))) unsigned int*)(sbase + (size_t)(kt + 32) * sstep),
                (__attribute__((address_space(3))) unsigned int*)(dbase + (cur ^ 1) * 1024), 16, 0, 0);
        }

        // K fragments from LDS (A-operand): row = key, 16B chunk lq
        f16x8 kf0 = *reinterpret_cast<const f16x8*>(&Ks[cur][lr * 32 + lq * 8]);
        f16x8 kf1 = *reinterpret_cast<const f16x8*>(&Ks[cur][(16 + lr) * 32 + lq * 8]);

        f16x8 pa[2];
        #pragma unroll
        for (int t = 0; t < 2; t++) {
            f32x4 z = {};
            // S^T (log2 units): lane holds q=lr; s0[r]=key kt+4lq+r, s1[r]=key kt+16+4lq+r
            f32x4 s0 = __builtin_amdgcn_mfma_f32_16x16x32_f16(kf0, qf[t], z, 0, 0, 0);
            f32x4 s1 = __builtin_amdgcn_mfma_f32_16x16x32_f16(kf1, qf[t], z, 0, 0, 0);

            float tm = fmaxf(fmaxf(fmaxf(s0[0], s0[1]), fmaxf(s0[2], s0[3])),
                             fmaxf(fmaxf(s1[0], s1[1]), fmaxf(s1[2], s1[3])));
            tm = fmaxf(tm, __shfl_xor(tm, 16, 64));
            tm = fmaxf(tm, __shfl_xor(tm, 32, 64));

            bool nr = __all(tm <= m[t]);           // defer-max
            float mn = nr ? m[t] : fmaxf(m[t], tm);
            float scl = exp2f(m[t] - mn);
            m[t] = mn;

            float p0 = exp2f(s0[0] - mn), p1 = exp2f(s0[1] - mn);
            float p2 = exp2f(s0[2] - mn), p3 = exp2f(s0[3] - mn);
            float p4 = exp2f(s1[0] - mn), p5 = exp2f(s1[1] - mn);
            float p6 = exp2f(s1[2] - mn), p7 = exp2f(s1[3] - mn);
            float rs = ((p0 + p1) + (p2 + p3)) + ((p4 + p5) + (p6 + p7));
            rs += __shfl_xor(rs, 16, 64);
            rs += __shfl_xor(rs, 32, 64);
            l[t] = l[t] * scl + rs;

            int pkA0 = __builtin_bit_cast(int, __builtin_amdgcn_cvt_pkrtz(p0, p1));
            int pkA1 = __builtin_bit_cast(int, __builtin_amdgcn_cvt_pkrtz(p2, p3));
            int pkB0 = __builtin_bit_cast(int, __builtin_amdgcn_cvt_pkrtz(p4, p5));
            int pkB1 = __builtin_bit_cast(int, __builtin_amdgcn_cvt_pkrtz(p6, p7));
            int4 pvi = {pkA0, pkA1, pkB0, pkB1};
            pa[t] = __builtin_bit_cast(f16x8, pvi);

            if (!nr) {
                #pragma unroll
                for (int r = 0; r < 4; r++) {
                    float scr = __shfl(scl, lq * 4 + r, 16);
                    O[t][0][r] *= scr;
                    O[t][1][r] *= scr;
                }
            }
        }

        // V fragments from LDS with the same key permutation: d = lr (+16),
        // slot j<4 -> key kt+4lq+j ; j>=4 -> key kt+16+4lq+j
        uint2 va0 = *reinterpret_cast<const uint2*>(&Vs[cur][lr * 32 + lq * 4]);
        uint2 va1 = *reinterpret_cast<const uint2*>(&Vs[cur][lr * 32 + 16 + lq * 4]);
        uint2 vb0 = *reinterpret_cast<const uint2*>(&Vs[cur][(16 + lr) * 32 + lq * 4]);
        uint2 vb1 = *reinterpret_cast<const uint2*>(&Vs[cur][(16 + lr) * 32 + 16 + lq * 4]);
        int4 vi0 = {(int)va0.x, (int)va0.y, (int)va1.x, (int)va1.y};
        int4 vi1 = {(int)vb0.x, (int)vb0.y, (int)vb1.x, (int)vb1.y};
        f16x8 vf0 = __builtin_bit_cast(f16x8, vi0);
        f16x8 vf1 = __builtin_bit_cast(f16x8, vi1);

        #pragma unroll
        for (int t = 0; t < 2; t++) {
            O[t][0] = __builtin_amdgcn_mfma_f32_16x16x32_f16(pa[t], vf0, O[t][0], 0, 0, 0);
            O[t][1] = __builtin_amdgcn_mfma_f32_16x16x32_f16(pa[t], vf1, O[t][1], 0, 0, 0);
        }

        __syncthreads();   // drains stage vmcnt + protects buffer swap
    }

    // epilogue: O rows q = lq*4+r, cols d = lr (+16); l lives at lane (q) of each 16-group
    float* obase = out + (size_t)(b * SEQ) * DIM + (g * HPG + w) * HD;
    #pragma unroll
    for (int t = 0; t < 2; t++) {
        #pragma unroll
        for (int r = 0; r < 4; r++) {
            float lrow = __shfl(l[t], lq * 4 + r, 16);
            float inv = 1.0f / lrow;
            int row = q0 + t * 16 + lq * 4 + r;
            obase[(size_t)row * DIM + lr]      = O[t][0][r] * inv;
            obase[(size_t)row * DIM + 16 + lr] = O[t][1][r] * inv;
        }
    }
}

extern "C" void kernel_launch(void* const* d_in, const int* in_sizes, int n_in,
                              void* d_out, int out_size, void* d_ws, size_t ws_size,
                              hipStream_t stream) {
    const float* x  = (const float*)d_in[0];
    const float* wq = (const float*)d_in[1];
    const float* wk = (const float*)d_in[2];
    const float* wv = (const float*)d_in[3];
    float* out = (float*)d_out;

    unsigned short* ws  = (unsigned short*)d_ws;
    unsigned short* xb  = ws;                                  // 4096*1024
    unsigned short* wb  = xb + (size_t)BS * SEQ * DIM;         // 1536*1024
    unsigned short* qb  = wb + (size_t)NTOT * DIM;             // 4096*1024
    unsigned short* kb  = qb + (size_t)BS * SEQ * DIM;         // 4096*256
    unsigned short* vtb = kb + (size_t)BS * SEQ * KVD;         // 4096*256 (transposed)

    cvt_kernel<<<1024, 256, 0, stream>>>(x, xb, BS * SEQ * DIM);
    cvt_kernel<<<256,  256, 0, stream>>>(wq, wb, DIM * DIM);
    cvt_kernel<<<64,   256, 0, stream>>>(wk, wb + (size_t)DIM * DIM, KVD * DIM);
    cvt_kernel<<<64,   256, 0, stream>>>(wv, wb + (size_t)DIM * DIM + (size_t)KVD * DIM, KVD * DIM);

    qkv_gemm<<<dim3(NTOT / 64, BS * SEQ / 128), 256, 0, stream>>>(xb, wb, qb, kb, vtb);
    gqa_attn<<<BS * G * (SEQ / 32), 256, 0, stream>>>(qb, kb, vtb, out);
}

// Round 6
// 190.602 us; speedup vs baseline: 2.2434x; 1.2384x over previous
//
#include <hip/hip_runtime.h>
#include <hip/hip_bf16.h>

#define BS   2
#define SEQ  2048
#define DIM  1024
#define HD   32
#define G    8
#define HPG  4
#define KVD  256
#define NTOT (DIM + 2*KVD)   // 1536 output cols of the fused QKV GEMM

typedef __attribute__((ext_vector_type(8))) _Float16 f16x8;
typedef __attribute__((ext_vector_type(4))) float f32x4;

__device__ __forceinline__ unsigned short f2h(float f) {
    _Float16 h = (_Float16)f;
    return __builtin_bit_cast(unsigned short, h);
}

__device__ __forceinline__ float fexp2(float x) { return __builtin_amdgcn_exp2f(x); }

// ---------------- fp32 -> fp16 convert (vectorized, grid-stride) ----------------
__global__ __launch_bounds__(256) void cvt_kernel(const float* __restrict__ in,
                                                  unsigned short* __restrict__ out, int n) {
    int nv = n >> 2;
    for (int i = blockIdx.x * blockDim.x + threadIdx.x; i < nv; i += gridDim.x * blockDim.x) {
        float4 v = reinterpret_cast<const float4*>(in)[i];
        ushort4 o;
        o.x = f2h(v.x); o.y = f2h(v.y); o.z = f2h(v.z); o.w = f2h(v.w);
        reinterpret_cast<ushort4*>(out)[i] = o;
    }
}

// ---------------- fused QKV projection GEMM ----------------
__global__ __launch_bounds__(256) void qkv_gemm(const unsigned short* __restrict__ xb,
                                                const unsigned short* __restrict__ wb,
                                                unsigned short* __restrict__ qb,
                                                unsigned short* __restrict__ kb,
                                                unsigned short* __restrict__ vtb) {
    int lane = threadIdx.x & 63;
    int w    = threadIdx.x >> 6;
    int m0   = blockIdx.y * 128 + w * 16;
    int n0   = blockIdx.x * 64;
    int lr = lane & 15, lq = lane >> 4;

    f32x4 acc[2][4] = {};
    const unsigned short* xrow0 = xb + (m0 + lr) * DIM + lq * 8;
    const unsigned short* xrow1 = xrow0 + 64 * DIM;
    for (int ks = 0; ks < DIM; ks += 32) {
        f16x8 a0 = *reinterpret_cast<const f16x8*>(xrow0 + ks);
        f16x8 a1 = *reinterpret_cast<const f16x8*>(xrow1 + ks);
        #pragma unroll
        for (int nf = 0; nf < 4; nf++) {
            const unsigned short* wrow = wb + (n0 + nf * 16 + lr) * DIM + ks + lq * 8;
            f16x8 bfr = *reinterpret_cast<const f16x8*>(wrow);
            acc[0][nf] = __builtin_amdgcn_mfma_f32_16x16x32_f16(a0, bfr, acc[0][nf], 0, 0, 0);
            acc[1][nf] = __builtin_amdgcn_mfma_f32_16x16x32_f16(a1, bfr, acc[1][nf], 0, 0, 0);
        }
    }
    #pragma unroll
    for (int mi = 0; mi < 2; mi++) {
        #pragma unroll
        for (int nf = 0; nf < 4; nf++) {
            int col = n0 + nf * 16 + lr;
            #pragma unroll
            for (int r = 0; r < 4; r++) {
                int row = m0 + mi * 64 + lq * 4 + r;
                unsigned short v = f2h(acc[mi][nf][r]);
                if (col < DIM) {
                    qb[row * DIM + col] = v;
                } else if (col < DIM + KVD) {
                    kb[row * KVD + (col - DIM)] = v;
                } else {
                    int b = row >> 11, s = row & 2047;
                    vtb[(b * KVD + (col - DIM - KVD)) * SEQ + s] = v;
                }
            }
        }
    }
}

// ---------------- flash-style GQA attention ----------------
// block = (b, g, 32 q-rows); 4 waves = 4 heads sharing K/V. Triple-buffered LDS staging
// via global_load_lds(16B) with counted vmcnt(1) (never drained in-loop) + raw s_barrier.
// 16B-chunk XOR swizzle c' = c ^ ((row>>1)&3) on BOTH stage-source and ds_reads
// (bank-conflict-free K b128 and V b64 reads; gload_lds dest stays linear).
// Swapped QK^T -> in-register softmax (native v_exp_f32); transposed PV
// (O^T = mfma(V^T, P^T)) makes rescale + 1/l lane-local and stores float4.
__global__ __launch_bounds__(256) void gqa_attn(const unsigned short* __restrict__ qb,
                                                const unsigned short* __restrict__ kb,
                                                const unsigned short* __restrict__ vtb,
                                                float* __restrict__ out) {
    __shared__ unsigned short Ks[3][32 * 32];   // [buf][key][32 dims], chunk-swizzled
    __shared__ unsigned short Vs[3][32 * 32];   // [buf][d]  [32 keys], chunk-swizzled

    int tid  = threadIdx.x;
    int lane = tid & 63;
    int w    = tid >> 6;
    int bi   = blockIdx.x;
    int qt = bi & 63;
    int g  = (bi >> 6) & 7;
    int b  = bi >> 9;
    int q0 = qt * 32;
    int lr = lane & 15, lq = lane >> 4;
    int h3r = (lr >> 1) & 3;                    // read-side swizzle key

    const unsigned short* kbase = kb + b * SEQ * KVD + g * HD;
    const unsigned short* vbase = vtb + (b * KVD + g * HD) * SEQ;

    // staging: threads 0-127 stage K, 128-255 stage V; 16B/thread/tile.
    // thread ci covers (row = ci>>2, slot c = ci&3) holding global chunk c ^ ((row>>1)&3).
    bool isK = tid < 128;
    int ci   = isK ? tid : tid - 128;
    int srow = ci >> 2;
    int scg  = (ci & 3) ^ ((ci >> 3) & 3);
    const unsigned short* sbase = isK ? (kbase + srow * KVD + scg * 8)
                                      : (vbase + srow * SEQ + scg * 8);
    int sstep = isK ? (32 * KVD) : 32;          // global advance per tile
    unsigned short* db0 = isK ? &Ks[0][ci * 8] : &Vs[0][ci * 8];

    #define STAGE(tile, buf)  __builtin_amdgcn_global_load_lds( \
        (const __attribute__((address_space(1))) unsigned int*)(sbase + (size_t)(tile) * sstep), \
        (__attribute__((address_space(3))) unsigned int*)(db0 + (buf) * 1024), 16, 0, 0)

    STAGE(0, 0);
    STAGE(1, 1);

    // Q fragments (B-operand), pre-scaled by log2(e) for native exp2
    f16x8 qf[2];
    #pragma unroll
    for (int t = 0; t < 2; t++) {
        qf[t] = *reinterpret_cast<const f16x8*>(
            qb + (b * SEQ + q0 + t * 16 + lr) * DIM + (g * HPG + w) * HD + lq * 8);
        qf[t] = qf[t] * (_Float16)1.44269504f;
    }

    f32x4 O[2][2] = {};
    float m[2] = {-1e30f, -1e30f}, l[2] = {0.f, 0.f};

    // precomputed swizzled LDS read offsets (elements)
    int koff = lr * 32 + ((lq ^ h3r) * 8);
    int c0 = (lq >> 1) ^ h3r;
    int voff0 = lr * 32 + c0 * 8 + (lq & 1) * 4;           // o = lq
    int voff1 = lr * 32 + (c0 ^ 2) * 8 + (lq & 1) * 4;     // o = 4+lq

    for (int i = 0; i < SEQ / 32; i++) {
        if (i < SEQ / 32 - 1) asm volatile("s_waitcnt vmcnt(1)" ::: "memory");
        else                  asm volatile("s_waitcnt vmcnt(0)" ::: "memory");
        __builtin_amdgcn_s_barrier();
        if (i + 2 < SEQ / 32) STAGE(i + 2, (i + 2) % 3);

        int cur = i % 3;
        const unsigned short* Kc = &Ks[cur][0];
        const unsigned short* Vc = &Vs[cur][0];

        f16x8 kf0 = *reinterpret_cast<const f16x8*>(Kc + koff);
        f16x8 kf1 = *reinterpret_cast<const f16x8*>(Kc + 16 * 32 + koff);

        f16x8 pa[2];
        #pragma unroll
        for (int t = 0; t < 2; t++) {
            f32x4 z = {};
            // S^T (log2 units): lane holds q=lr; s0[r]=key 4lq+r, s1[r]=key 16+4lq+r
            f32x4 s0 = __builtin_amdgcn_mfma_f32_16x16x32_f16(kf0, qf[t], z, 0, 0, 0);
            f32x4 s1 = __builtin_amdgcn_mfma_f32_16x16x32_f16(kf1, qf[t], z, 0, 0, 0);

            float tm = fmaxf(fmaxf(fmaxf(s0[0], s0[1]), fmaxf(s0[2], s0[3])),
                             fmaxf(fmaxf(s1[0], s1[1]), fmaxf(s1[2], s1[3])));
            tm = fmaxf(tm, __shfl_xor(tm, 16, 64));
            tm = fmaxf(tm, __shfl_xor(tm, 32, 64));

            bool nr = __all(tm <= m[t]);           // defer-max
            float mn = nr ? m[t] : fmaxf(m[t], tm);
            float scl = fexp2(m[t] - mn);
            m[t] = mn;

            float p0 = fexp2(s0[0] - mn), p1 = fexp2(s0[1] - mn);
            float p2 = fexp2(s0[2] - mn), p3 = fexp2(s0[3] - mn);
            float p4 = fexp2(s1[0] - mn), p5 = fexp2(s1[1] - mn);
            float p6 = fexp2(s1[2] - mn), p7 = fexp2(s1[3] - mn);
            float rs = ((p0 + p1) + (p2 + p3)) + ((p4 + p5) + (p6 + p7));
            rs += __shfl_xor(rs, 16, 64);
            rs += __shfl_xor(rs, 32, 64);
            l[t] = l[t] * scl + rs;

            int pkA0 = __builtin_bit_cast(int, __builtin_amdgcn_cvt_pkrtz(p0, p1));
            int pkA1 = __builtin_bit_cast(int, __builtin_amdgcn_cvt_pkrtz(p2, p3));
            int pkB0 = __builtin_bit_cast(int, __builtin_amdgcn_cvt_pkrtz(p4, p5));
            int pkB1 = __builtin_bit_cast(int, __builtin_amdgcn_cvt_pkrtz(p6, p7));
            int4 pvi = {pkA0, pkA1, pkB0, pkB1};
            pa[t] = __builtin_bit_cast(f16x8, pvi);

            if (!nr) {                              // lane-local rescale (O^T cols = q = lr)
                O[t][0] *= scl;
                O[t][1] *= scl;
            }
        }

        // V fragments (A-operand, V^T rows d = lr / 16+lr) with matching key permutation
        uint2 va0 = *reinterpret_cast<const uint2*>(Vc + voff0);
        uint2 va1 = *reinterpret_cast<const uint2*>(Vc + voff1);
        uint2 vb0 = *reinterpret_cast<const uint2*>(Vc + 16 * 32 + voff0);
        uint2 vb1 = *reinterpret_cast<const uint2*>(Vc + 16 * 32 + voff1);
        int4 vi0 = {(int)va0.x, (int)va0.y, (int)va1.x, (int)va1.y};
        int4 vi1 = {(int)vb0.x, (int)vb0.y, (int)vb1.x, (int)vb1.y};
        f16x8 vf0 = __builtin_bit_cast(f16x8, vi0);
        f16x8 vf1 = __builtin_bit_cast(f16x8, vi1);

        // transposed PV: O^T[d][q] += V^T * P^T ; C cols = q = lr (lane-local)
        #pragma unroll
        for (int t = 0; t < 2; t++) {
            O[t][0] = __builtin_amdgcn_mfma_f32_16x16x32_f16(vf0, pa[t], O[t][0], 0, 0, 0);
            O[t][1] = __builtin_amdgcn_mfma_f32_16x16x32_f16(vf1, pa[t], O[t][1], 0, 0, 0);
        }
    }

    // epilogue: lane holds O^T[d = lq*4+r (+16)][q = lr]; all lane-local, float4 stores
    float* obase = out + (size_t)(b * SEQ) * DIM + (g * HPG + w) * HD;
    #pragma unroll
    for (int t = 0; t < 2; t++) {
        float inv = 1.0f / l[t];
        size_t rowoff = (size_t)(q0 + t * 16 + lr) * DIM;
        float4 o0 = {O[t][0][0] * inv, O[t][0][1] * inv, O[t][0][2] * inv, O[t][0][3] * inv};
        float4 o1 = {O[t][1][0] * inv, O[t][1][1] * inv, O[t][1][2] * inv, O[t][1][3] * inv};
        *reinterpret_cast<float4*>(obase + rowoff + lq * 4)      = o0;
        *reinterpret_cast<float4*>(obase + rowoff + 16 + lq * 4) = o1;
    }
}

extern "C" void kernel_launch(void* const* d_in, const int* in_sizes, int n_in,
                              void* d_out, int out_size, void* d_ws, size_t ws_size,
                              hipStream_t stream) {
    const float* x  = (const float*)d_in[0];
    const float* wq = (const float*)d_in[1];
    const float* wk = (const float*)d_in[2];
    const float* wv = (const float*)d_in[3];
    float* out = (float*)d_out;

    unsigned short* ws  = (unsigned short*)d_ws;
    unsigned short* xb  = ws;                                  // 4096*1024
    unsigned short* wb  = xb + (size_t)BS * SEQ * DIM;         // 1536*1024
    unsigned short* qb  = wb + (size_t)NTOT * DIM;             // 4096*1024
    unsigned short* kb  = qb + (size_t)BS * SEQ * DIM;         // 4096*256
    unsigned short* vtb = kb + (size_t)BS * SEQ * KVD;         // 4096*256 (transposed)

    cvt_kernel<<<1024, 256, 0, stream>>>(x, xb, BS * SEQ * DIM);
    cvt_kernel<<<256,  256, 0, stream>>>(wq, wb, DIM * DIM);
    cvt_kernel<<<64,   256, 0, stream>>>(wk, wb + (size_t)DIM * DIM, KVD * DIM);
    cvt_kernel<<<64,   256, 0, stream>>>(wv, wb + (size_t)DIM * DIM + (size_t)KVD * DIM, KVD * DIM);

    qkv_gemm<<<dim3(NTOT / 64, BS * SEQ / 128), 256, 0, stream>>>(xb, wb, qb, kb, vtb);
    gqa_attn<<<BS * G * (SEQ / 32), 256, 0, stream>>>(qb, kb, vtb, out);
}

// Round 7
// 169.925 us; speedup vs baseline: 2.5164x; 1.1217x over previous
//
#include <hip/hip_runtime.h>
#include <hip/hip_bf16.h>

#define BS   2
#define SEQ  2048
#define DIM  1024
#define HD   32
#define G    8
#define HPG  4
#define KVD  256
#define NTOT (DIM + 2*KVD)   // 1536 output cols of the fused QKV GEMM
#define NT   (SEQ / 64)      // 32 KV tiles of 64 keys

typedef __attribute__((ext_vector_type(8))) _Float16 f16x8;
typedef __attribute__((ext_vector_type(4))) float f32x4;

__device__ __forceinline__ unsigned short f2h(float f) {
    _Float16 h = (_Float16)f;
    return __builtin_bit_cast(unsigned short, h);
}

__device__ __forceinline__ float fexp2(float x) { return __builtin_amdgcn_exp2f(x); }

// ---------------- fp32 -> fp16 convert (vectorized, grid-stride) ----------------
__global__ __launch_bounds__(256) void cvt_kernel(const float* __restrict__ in,
                                                  unsigned short* __restrict__ out, int n) {
    int nv = n >> 2;
    for (int i = blockIdx.x * blockDim.x + threadIdx.x; i < nv; i += gridDim.x * blockDim.x) {
        float4 v = reinterpret_cast<const float4*>(in)[i];
        ushort4 o;
        o.x = f2h(v.x); o.y = f2h(v.y); o.z = f2h(v.z); o.w = f2h(v.w);
        reinterpret_cast<ushort4*>(out)[i] = o;
    }
}

// ---------------- fused QKV projection GEMM ----------------
// V epilogue stores vtb pi-permuted per 32-key block: key w -> slot
// (w & ~31) + ((w>>2)&3)*8 + (w>>4 & 1)*4 + (w&3), so each 16B chunk a of a
// 32-block holds keys {4a..4a+3, 16+4a..16+4a+3} — exactly one PV A-frag group.
__global__ __launch_bounds__(256) void qkv_gemm(const unsigned short* __restrict__ xb,
                                                const unsigned short* __restrict__ wb,
                                                unsigned short* __restrict__ qb,
                                                unsigned short* __restrict__ kb,
                                                unsigned short* __restrict__ vtb) {
    int lane = threadIdx.x & 63;
    int w    = threadIdx.x >> 6;
    int m0   = blockIdx.y * 128 + w * 16;
    int n0   = blockIdx.x * 64;
    int lr = lane & 15, lq = lane >> 4;

    f32x4 acc[2][4] = {};
    const unsigned short* xrow0 = xb + (m0 + lr) * DIM + lq * 8;
    const unsigned short* xrow1 = xrow0 + 64 * DIM;
    for (int ks = 0; ks < DIM; ks += 32) {
        f16x8 a0 = *reinterpret_cast<const f16x8*>(xrow0 + ks);
        f16x8 a1 = *reinterpret_cast<const f16x8*>(xrow1 + ks);
        #pragma unroll
        for (int nf = 0; nf < 4; nf++) {
            const unsigned short* wrow = wb + (n0 + nf * 16 + lr) * DIM + ks + lq * 8;
            f16x8 bfr = *reinterpret_cast<const f16x8*>(wrow);
            acc[0][nf] = __builtin_amdgcn_mfma_f32_16x16x32_f16(a0, bfr, acc[0][nf], 0, 0, 0);
            acc[1][nf] = __builtin_amdgcn_mfma_f32_16x16x32_f16(a1, bfr, acc[1][nf], 0, 0, 0);
        }
    }
    #pragma unroll
    for (int mi = 0; mi < 2; mi++) {
        #pragma unroll
        for (int nf = 0; nf < 4; nf++) {
            int col = n0 + nf * 16 + lr;
            #pragma unroll
            for (int r = 0; r < 4; r++) {
                int row = m0 + mi * 64 + lq * 4 + r;
                unsigned short v = f2h(acc[mi][nf][r]);
                if (col < DIM) {
                    qb[row * DIM + col] = v;
                } else if (col < DIM + KVD) {
                    kb[row * KVD + (col - DIM)] = v;
                } else {
                    int b = row >> 11, s = row & 2047;
                    int ps = (s & ~31) + ((s >> 2) & 3) * 8 + ((s >> 4) & 1) * 4 + (s & 3);
                    vtb[(b * KVD + (col - DIM - KVD)) * SEQ + ps] = v;
                }
            }
        }
    }
}

// ---------------- flash-style GQA attention ----------------
// block = (b, g, 32 q-rows); 4 waves = 4 heads sharing K/V. KVBLK=64, 32 iters.
// Triple-buffered LDS staging via global_load_lds(16B), counted vmcnt(2), raw s_barrier.
// Swapped QK^T: lane (lq,lr) holds q-row lr, keys {4lq+r, 16+4lq+r, 32+4lq+r, 48+4lq+r}.
// Defer-max (THR=8 log2-units) skips max-tree+rescale; l is per-lane partial, reduced once
// at the end. pi-permuted V makes PV A-frags single b128 LDS reads (XOR-swizzled).
// Transposed PV (O^T = mfma(V^T, P^T)): rescale, 1/l, and float4 stores all lane-local.
__global__ __launch_bounds__(256) void gqa_attn(const unsigned short* __restrict__ qb,
                                                const unsigned short* __restrict__ kb,
                                                const unsigned short* __restrict__ vtb,
                                                float* __restrict__ out) {
    __shared__ unsigned short Ks[3][64 * 32];   // [buf][key][32 dims], chunk-swizzled
    __shared__ unsigned short Vs[3][32 * 64];   // [buf][d][64 keys pi-order], chunk-swizzled

    int tid  = threadIdx.x;
    int lane = tid & 63;
    int w    = tid >> 6;
    int bi   = blockIdx.x;
    int qt = bi & 63;
    int g  = (bi >> 6) & 7;
    int b  = bi >> 9;
    int q0 = qt * 32;
    int lr = lane & 15, lq = lane >> 4;

    const unsigned short* kbase = kb + b * SEQ * KVD + g * HD;
    const unsigned short* vbase = vtb + (b * KVD + g * HD) * SEQ;

    // staging: every thread stages one K chunk and one V chunk per tile (16B each)
    int krow = tid >> 2, kc = tid & 3;
    int kscg = kc ^ ((krow >> 1) & 3);
    const unsigned short* srcK = kbase + krow * KVD + kscg * 8;
    int vd = tid >> 3, vc = tid & 7;
    int vscg = vc ^ (vd & 7);
    const unsigned short* srcV = vbase + vd * SEQ + vscg * 8;
    unsigned short* dstK0 = &Ks[0][tid * 8];
    unsigned short* dstV0 = &Vs[0][tid * 8];

    #define STAGE(tile, buf) do { \
        __builtin_amdgcn_global_load_lds( \
            (const __attribute__((address_space(1))) unsigned int*)(srcK + (size_t)(tile) * 64 * KVD), \
            (__attribute__((address_space(3))) unsigned int*)(dstK0 + (buf) * 2048), 16, 0, 0); \
        __builtin_amdgcn_global_load_lds( \
            (const __attribute__((address_space(1))) unsigned int*)(srcV + (size_t)(tile) * 64), \
            (__attribute__((address_space(3))) unsigned int*)(dstV0 + (buf) * 2048), 16, 0, 0); \
    } while (0)

    // Q fragments (B-operand), pre-scaled by log2(e) for native exp2
    f16x8 qf[2];
    #pragma unroll
    for (int t = 0; t < 2; t++) {
        qf[t] = *reinterpret_cast<const f16x8*>(
            qb + (b * SEQ + q0 + t * 16 + lr) * DIM + (g * HPG + w) * HD + lq * 8);
        qf[t] = qf[t] * (_Float16)1.44269504f;
    }

    STAGE(0, 0);
    STAGE(1, 1);

    f32x4 O[2][2] = {};
    float m[2] = {-1e30f, -1e30f}, l[2] = {0.f, 0.f};

    // swizzled LDS read offsets (elements)
    int koff  = lr * 32 + ((lq ^ ((lr >> 1) & 3)) * 8);          // K: key=lr(+16s), chunk lq
    int voffA = lr * 64 + ((lq ^ (lr & 7)) * 8);                 // V: d=lr(+16), pi-chunk lq
    int voffB = lr * 64 + (((4 + lq) ^ (lr & 7)) * 8);           //    pi-chunk 4+lq

    for (int i = 0; i < NT; i++) {
        if (i < NT - 1) asm volatile("s_waitcnt vmcnt(2)" ::: "memory");
        else            asm volatile("s_waitcnt vmcnt(0)" ::: "memory");
        __builtin_amdgcn_s_barrier();
        if (i + 2 < NT) STAGE(i + 2, (i + 2) % 3);

        const unsigned short* Kc = &Ks[i % 3][0];
        const unsigned short* Vc = &Vs[i % 3][0];

        f16x8 kf0 = *reinterpret_cast<const f16x8*>(Kc + koff);            // keys lr
        f16x8 kf1 = *reinterpret_cast<const f16x8*>(Kc + 512 + koff);      // keys 16+lr
        f16x8 kf2 = *reinterpret_cast<const f16x8*>(Kc + 1024 + koff);     // keys 32+lr
        f16x8 kf3 = *reinterpret_cast<const f16x8*>(Kc + 1536 + koff);     // keys 48+lr

        f16x8 vfA0 = *reinterpret_cast<const f16x8*>(Vc + voffA);          // d=lr,   keys pi1
        f16x8 vfB0 = *reinterpret_cast<const f16x8*>(Vc + voffB);          // d=lr,   keys pi2
        f16x8 vfA1 = *reinterpret_cast<const f16x8*>(Vc + 1024 + voffA);   // d=16+lr, pi1
        f16x8 vfB1 = *reinterpret_cast<const f16x8*>(Vc + 1024 + voffB);   // d=16+lr, pi2

        #pragma unroll
        for (int t = 0; t < 2; t++) {
            f32x4 z = {};
            // S^T (log2 units): lane holds q=lr; s_k[r] = key 16k + 4lq + r
            f32x4 s0 = __builtin_amdgcn_mfma_f32_16x16x32_f16(kf0, qf[t], z, 0, 0, 0);
            f32x4 s1 = __builtin_amdgcn_mfma_f32_16x16x32_f16(kf1, qf[t], z, 0, 0, 0);
            f32x4 s2 = __builtin_amdgcn_mfma_f32_16x16x32_f16(kf2, qf[t], z, 0, 0, 0);
            f32x4 s3 = __builtin_amdgcn_mfma_f32_16x16x32_f16(kf3, qf[t], z, 0, 0, 0);

            // local max over this lane's 16 keys
            float tm = fmaxf(
                fmaxf(fmaxf(fmaxf(s0[0], s0[1]), fmaxf(s0[2], s0[3])),
                      fmaxf(fmaxf(s1[0], s1[1]), fmaxf(s1[2], s1[3]))),
                fmaxf(fmaxf(fmaxf(s2[0], s2[1]), fmaxf(s2[2], s2[3])),
                      fmaxf(fmaxf(s3[0], s3[1]), fmaxf(s3[2], s3[3]))));

            if (!__all(tm <= m[t] + 8.f)) {        // defer-max: rare slow path
                float tw = fmaxf(tm, __shfl_xor(tm, 16, 64));
                tw = fmaxf(tw, __shfl_xor(tw, 32, 64));
                float mn = fmaxf(m[t], tw);
                float scl = fexp2(m[t] - mn);
                m[t] = mn;
                l[t] *= scl;
                O[t][0] *= scl;
                O[t][1] *= scl;
            }

            float mt = m[t];
            float p00 = fexp2(s0[0] - mt), p01 = fexp2(s0[1] - mt);
            float p02 = fexp2(s0[2] - mt), p03 = fexp2(s0[3] - mt);
            float p10 = fexp2(s1[0] - mt), p11 = fexp2(s1[1] - mt);
            float p12 = fexp2(s1[2] - mt), p13 = fexp2(s1[3] - mt);
            float p20 = fexp2(s2[0] - mt), p21 = fexp2(s2[1] - mt);
            float p22 = fexp2(s2[2] - mt), p23 = fexp2(s2[3] - mt);
            float p30 = fexp2(s3[0] - mt), p31 = fexp2(s3[1] - mt);
            float p32 = fexp2(s3[2] - mt), p33 = fexp2(s3[3] - mt);

            // per-lane partial l (own 16 keys only; cross-lane reduce once at end)
            l[t] += (((p00 + p01) + (p02 + p03)) + ((p10 + p11) + (p12 + p13)))
                  + (((p20 + p21) + (p22 + p23)) + ((p30 + p31) + (p32 + p33)));

            // P^T A..B-frags in-register; slot order matches pi-permuted V chunks
            int a0 = __builtin_bit_cast(int, __builtin_amdgcn_cvt_pkrtz(p00, p01));
            int a1 = __builtin_bit_cast(int, __builtin_amdgcn_cvt_pkrtz(p02, p03));
            int a2 = __builtin_bit_cast(int, __builtin_amdgcn_cvt_pkrtz(p10, p11));
            int a3 = __builtin_bit_cast(int, __builtin_amdgcn_cvt_pkrtz(p12, p13));
            int b0 = __builtin_bit_cast(int, __builtin_amdgcn_cvt_pkrtz(p20, p21));
            int b1 = __builtin_bit_cast(int, __builtin_amdgcn_cvt_pkrtz(p22, p23));
            int b2 = __builtin_bit_cast(int, __builtin_amdgcn_cvt_pkrtz(p30, p31));
            int b3 = __builtin_bit_cast(int, __builtin_amdgcn_cvt_pkrtz(p32, p33));
            int4 pi1 = {a0, a1, a2, a3};
            int4 pi2 = {b0, b1, b2, b3};
            f16x8 pa1 = __builtin_bit_cast(f16x8, pi1);
            f16x8 pa2 = __builtin_bit_cast(f16x8, pi2);

            // transposed PV: O^T[d][q] += V^T * P^T ; C cols = q = lr (lane-local)
            O[t][0] = __builtin_amdgcn_mfma_f32_16x16x32_f16(vfA0, pa1, O[t][0], 0, 0, 0);
            O[t][0] = __builtin_amdgcn_mfma_f32_16x16x32_f16(vfB0, pa2, O[t][0], 0, 0, 0);
            O[t][1] = __builtin_amdgcn_mfma_f32_16x16x32_f16(vfA1, pa1, O[t][1], 0, 0, 0);
            O[t][1] = __builtin_amdgcn_mfma_f32_16x16x32_f16(vfB1, pa2, O[t][1], 0, 0, 0);
        }
    }

    // epilogue: reduce per-lane l across the 4 lq-groups, then lane-local normalize+store
    float* obase = out + (size_t)(b * SEQ) * DIM + (g * HPG + w) * HD;
    #pragma unroll
    for (int t = 0; t < 2; t++) {
        float lt = l[t];
        lt += __shfl_xor(lt, 16, 64);
        lt += __shfl_xor(lt, 32, 64);
        float inv = 1.0f / lt;
        size_t rowoff = (size_t)(q0 + t * 16 + lr) * DIM;
        float4 o0 = {O[t][0][0] * inv, O[t][0][1] * inv, O[t][0][2] * inv, O[t][0][3] * inv};
        float4 o1 = {O[t][1][0] * inv, O[t][1][1] * inv, O[t][1][2] * inv, O[t][1][3] * inv};
        *reinterpret_cast<float4*>(obase + rowoff + lq * 4)      = o0;
        *reinterpret_cast<float4*>(obase + rowoff + 16 + lq * 4) = o1;
    }
    #undef STAGE
}

extern "C" void kernel_launch(void* const* d_in, const int* in_sizes, int n_in,
                              void* d_out, int out_size, void* d_ws, size_t ws_size,
                              hipStream_t stream) {
    const float* x  = (const float*)d_in[0];
    const float* wq = (const float*)d_in[1];
    const float* wk = (const float*)d_in[2];
    const float* wv = (const float*)d_in[3];
    float* out = (float*)d_out;

    unsigned short* ws  = (unsigned short*)d_ws;
    unsigned short* xb  = ws;                                  // 4096*1024
    unsigned short* wb  = xb + (size_t)BS * SEQ * DIM;         // 1536*1024
    unsigned short* qb  = wb + (size_t)NTOT * DIM;             // 4096*1024
    unsigned short* kb  = qb + (size_t)BS * SEQ * DIM;         // 4096*256
    unsigned short* vtb = kb + (size_t)BS * SEQ * KVD;         // 4096*256 (pi-transposed)

    cvt_kernel<<<1024, 256, 0, stream>>>(x, xb, BS * SEQ * DIM);
    cvt_kernel<<<256,  256, 0, stream>>>(wq, wb, DIM * DIM);
    cvt_kernel<<<64,   256, 0, stream>>>(wk, wb + (size_t)DIM * DIM, KVD * DIM);
    cvt_kernel<<<64,   256, 0, stream>>>(wv, wb + (size_t)DIM * DIM + (size_t)KVD * DIM, KVD * DIM);

    qkv_gemm<<<dim3(NTOT / 64, BS * SEQ / 128), 256, 0, stream>>>(xb, wb, qb, kb, vtb);
    gqa_attn<<<BS * G * (SEQ / 32), 256, 0, stream>>>(qb, kb, vtb, out);
}

// Round 8
// 115.457 us; speedup vs baseline: 3.7035x; 1.4718x over previous
//
#include <hip/hip_runtime.h>
#include <hip/hip_bf16.h>

#define BS   2
#define SEQ  2048
#define DIM  1024
#define HD   32
#define G    8
#define HPG  4
#define KVD  256
#define NTOT (DIM + 2*KVD)   // 1536 output cols of the fused QKV GEMM
#define NT   (SEQ / 128)     // 16 KV tiles of 128 keys

typedef __attribute__((ext_vector_type(8))) _Float16 f16x8;
typedef __attribute__((ext_vector_type(4))) float f32x4;

__device__ __forceinline__ unsigned short f2h(float f) {
    _Float16 h = (_Float16)f;
    return __builtin_bit_cast(unsigned short, h);
}

__device__ __forceinline__ float fexp2(float x) { return __builtin_amdgcn_exp2f(x); }

#define GLDS(src, dst) __builtin_amdgcn_global_load_lds( \
    (const __attribute__((address_space(1))) unsigned int*)(src), \
    (__attribute__((address_space(3))) unsigned int*)(dst), 16, 0, 0)

// ---------------- fp32 -> fp16 convert: x (grid-stride) ----------------
__global__ __launch_bounds__(256) void cvt_x(const float* __restrict__ in,
                                             unsigned short* __restrict__ out, int n) {
    int nv = n >> 2;
    for (int i = blockIdx.x * blockDim.x + threadIdx.x; i < nv; i += gridDim.x * blockDim.x) {
        float4 v = reinterpret_cast<const float4*>(in)[i];
        ushort4 o;
        o.x = f2h(v.x); o.y = f2h(v.y); o.z = f2h(v.z); o.w = f2h(v.w);
        reinterpret_cast<ushort4*>(out)[i] = o;
    }
}

// ---------------- fused weight convert: wq|wk|wv -> wb (one launch) ----------------
__global__ __launch_bounds__(256) void cvt_w(const float* __restrict__ wq,
                                             const float* __restrict__ wk,
                                             const float* __restrict__ wv,
                                             unsigned short* __restrict__ out) {
    int i = blockIdx.x * 256 + threadIdx.x;              // float4 index, total 393216
    const float* src; int off;
    if (i < 262144)      { src = wq; off = i; }
    else if (i < 327680) { src = wk; off = i - 262144; }
    else                 { src = wv; off = i - 327680; }
    float4 v = reinterpret_cast<const float4*>(src)[off];
    ushort4 o;
    o.x = f2h(v.x); o.y = f2h(v.y); o.z = f2h(v.z); o.w = f2h(v.w);
    reinterpret_cast<ushort4*>(out)[i] = o;
}

// ---------------- fused QKV projection GEMM (m97-style LDS-staged) ----------------
// Y[m][n] = sum_k X[m][k]*W[n][k]; M=4096 N=1536 K=1024. BM=128 BN=64 BK=64.
// Grid 24x32 = 768 blocks (3/CU). 4 waves in 2x2; wave = 64x32 output (4x2 frags).
// A/B tiles staged via global_load_lds(16B), double-buffered, XOR-chunk swizzle
// c' = c ^ (row&7) applied on global source + ds_read (LDS dest linear).
// Epilogue routes cols: [0,1024)->qb, [1024,1280)->kb, [1280,1536)->vtb pi-permuted.
__global__ __launch_bounds__(256) void qkv_gemm(const unsigned short* __restrict__ xb,
                                                const unsigned short* __restrict__ wb,
                                                unsigned short* __restrict__ qb,
                                                unsigned short* __restrict__ kb,
                                                unsigned short* __restrict__ vtb) {
    __shared__ unsigned short As[2][128 * 64];
    __shared__ unsigned short Bs[2][64 * 64];

    int tid  = threadIdx.x;
    int lane = tid & 63;
    int w    = tid >> 6;
    int m0   = blockIdx.y * 128;
    int n0   = blockIdx.x * 64;
    int lr = lane & 15, lq = lane >> 4;
    int wr = w >> 1, wc = w & 1;

    // staging precompute: slot = tid + n*256; row=slot>>3, c=tid&7, g=c^((tid>>3)&7)
    int srow = tid >> 3;
    int sg   = (tid & 7) ^ (srow & 7);
    const unsigned short* srcA = xb + (size_t)(m0 + srow) * DIM + sg * 8;
    const unsigned short* srcB = wb + (size_t)(n0 + srow) * DIM + sg * 8;

    #define GSTAGE(kt, buf) do { \
        GLDS(srcA + (kt),            &As[buf][tid * 8]); \
        GLDS(srcA + (kt) + 32 * DIM, &As[buf][(tid + 256) * 8]); \
        GLDS(srcA + (kt) + 64 * DIM, &As[buf][(tid + 512) * 8]); \
        GLDS(srcA + (kt) + 96 * DIM, &As[buf][(tid + 768) * 8]); \
        GLDS(srcB + (kt),            &Bs[buf][tid * 8]); \
        GLDS(srcB + (kt) + 32 * DIM, &Bs[buf][(tid + 256) * 8]); \
    } while (0)

    GSTAGE(0, 0);

    f32x4 acc[4][2] = {};
    int swz = lr & 7;

    for (int i = 0; i < 16; i++) {
        asm volatile("s_waitcnt vmcnt(0)" ::: "memory");
        __builtin_amdgcn_s_barrier();
        if (i + 1 < 16) GSTAGE((i + 1) * 64, (i + 1) & 1);

        const unsigned short* Ac = &As[i & 1][0];
        const unsigned short* Bc = &Bs[i & 1][0];

        #pragma unroll
        for (int ks = 0; ks < 2; ks++) {
            int c = ks * 4 + lq;
            f16x8 a[4], bfr[2];
            #pragma unroll
            for (int mi = 0; mi < 4; mi++) {
                int row = wr * 64 + mi * 16 + lr;
                a[mi] = *reinterpret_cast<const f16x8*>(Ac + row * 64 + (c ^ swz) * 8);
            }
            #pragma unroll
            for (int nf = 0; nf < 2; nf++) {
                int row = wc * 32 + nf * 16 + lr;
                bfr[nf] = *reinterpret_cast<const f16x8*>(Bc + row * 64 + (c ^ swz) * 8);
            }
            #pragma unroll
            for (int mi = 0; mi < 4; mi++)
                #pragma unroll
                for (int nf = 0; nf < 2; nf++)
                    acc[mi][nf] = __builtin_amdgcn_mfma_f32_16x16x32_f16(a[mi], bfr[nf], acc[mi][nf], 0, 0, 0);
        }
    }

    #pragma unroll
    for (int mi = 0; mi < 4; mi++) {
        #pragma unroll
        for (int nf = 0; nf < 2; nf++) {
            int col = n0 + wc * 32 + nf * 16 + lr;
            #pragma unroll
            for (int r = 0; r < 4; r++) {
                int row = m0 + wr * 64 + mi * 16 + lq * 4 + r;
                unsigned short v = f2h(acc[mi][nf][r]);
                if (col < DIM) {
                    qb[row * DIM + col] = v;
                } else if (col < DIM + KVD) {
                    kb[row * KVD + (col - DIM)] = v;
                } else {
                    int b = row >> 11, s = row & 2047;
                    int ps = (s & ~31) + ((s >> 2) & 3) * 8 + ((s >> 4) & 1) * 4 + (s & 3);
                    vtb[(b * KVD + (col - DIM - KVD)) * SEQ + ps] = v;
                }
            }
        }
    }
    #undef GSTAGE
}

// ---------------- flash-style GQA attention ----------------
// block = (b, g, 32 q-rows); 4 waves = 4 heads sharing K/V. KVBLK=128, 16 iters.
// Double-buffered LDS staging via global_load_lds(16B), vmcnt(0)+barrier per iter.
// Swapped QK^T -> in-register softmax (defer-max THR=8, per-lane partial l);
// pi-permuted V + transposed PV keep everything lane-local; zero cross-lane in steady state.
__global__ __launch_bounds__(256) void gqa_attn(const unsigned short* __restrict__ qb,
                                                const unsigned short* __restrict__ kb,
                                                const unsigned short* __restrict__ vtb,
                                                float* __restrict__ out) {
    __shared__ unsigned short Ks[2][128 * 32];  // [buf][key][32 dims], chunk-swizzled
    __shared__ unsigned short Vs[2][32 * 128];  // [buf][d][128 keys pi-order], chunk-swizzled

    int tid  = threadIdx.x;
    int lane = tid & 63;
    int w    = tid >> 6;
    int bi   = blockIdx.x;
    int qt = bi & 63;
    int g  = (bi >> 6) & 7;
    int b  = bi >> 9;
    int q0 = qt * 32;
    int lr = lane & 15, lq = lane >> 4;

    const unsigned short* kbase = kb + b * SEQ * KVD + g * HD;
    const unsigned short* vbase = vtb + (b * KVD + g * HD) * SEQ;

    // staging: K slots (row=key 0..127, c 0..3): thread n-th issue row=(tid>>2)+64n, c=tid&3,
    //          swzK = (tid&3)^((tid>>3)&3). V slots (row=d 0..31, c 0..15): row=(tid>>4)+16n,
    //          c=tid&15, swzV = (tid&15)^((tid>>4)&7).
    int kr = tid >> 2;
    int swzK = (tid & 3) ^ ((tid >> 3) & 3);
    const unsigned short* srcK = kbase + kr * KVD + swzK * 8;
    int vr = tid >> 4;
    int swzV = (tid & 15) ^ ((tid >> 4) & 7);
    const unsigned short* srcV = vbase + vr * SEQ + swzV * 8;

    #define STAGE(tile, buf) do { \
        GLDS(srcK + (size_t)(tile) * 128 * KVD,            &Ks[buf][tid * 8]); \
        GLDS(srcK + (size_t)(tile) * 128 * KVD + 64 * KVD, &Ks[buf][(tid + 256) * 8]); \
        GLDS(srcV + (size_t)(tile) * 128,                  &Vs[buf][tid * 8]); \
        GLDS(srcV + (size_t)(tile) * 128 + 16 * SEQ,       &Vs[buf][(tid + 256) * 8]); \
    } while (0)

    STAGE(0, 0);

    // Q fragments (B-operand), pre-scaled by log2(e) for native exp2
    f16x8 qf[2];
    #pragma unroll
    for (int t = 0; t < 2; t++) {
        qf[t] = *reinterpret_cast<const f16x8*>(
            qb + (b * SEQ + q0 + t * 16 + lr) * DIM + (g * HPG + w) * HD + lq * 8);
        qf[t] = qf[t] * (_Float16)1.44269504f;
    }

    f32x4 O[2][2] = {};
    float m[2] = {-1e30f, -1e30f}, l[2] = {0.f, 0.f};

    int koff = lr * 32 + ((lq ^ ((lr >> 1) & 3)) * 8);   // K: key row lr (+16k), chunk lq

    for (int i = 0; i < NT; i++) {
        asm volatile("s_waitcnt vmcnt(0)" ::: "memory");
        __builtin_amdgcn_s_barrier();
        if (i + 1 < NT) STAGE(i + 1, (i + 1) & 1);

        const unsigned short* Kc = &Ks[i & 1][0];
        const unsigned short* Vc = &Vs[i & 1][0];

        f16x8 kf[8];
        #pragma unroll
        for (int kk = 0; kk < 8; kk++)
            kf[kk] = *reinterpret_cast<const f16x8*>(Kc + kk * 512 + koff);

        f16x8 vf[2][4];
        #pragma unroll
        for (int half = 0; half < 2; half++)
            #pragma unroll
            for (int kk2 = 0; kk2 < 4; kk2++)
                vf[half][kk2] = *reinterpret_cast<const f16x8*>(
                    Vc + half * 2048 + lr * 128 + (((kk2 * 4 + lq) ^ (lr & 7)) * 8));

        #pragma unroll
        for (int t = 0; t < 2; t++) {
            f32x4 z = {};
            f32x4 s[8];
            #pragma unroll
            for (int kk = 0; kk < 8; kk++)
                s[kk] = __builtin_amdgcn_mfma_f32_16x16x32_f16(kf[kk], qf[t], z, 0, 0, 0);

            // local max over this lane's 32 keys
            float tm = -1e30f;
            #pragma unroll
            for (int kk = 0; kk < 8; kk++)
                tm = fmaxf(tm, fmaxf(fmaxf(s[kk][0], s[kk][1]), fmaxf(s[kk][2], s[kk][3])));

            if (!__all(tm <= m[t] + 8.f)) {        // defer-max: rare slow path
                float tw = fmaxf(tm, __shfl_xor(tm, 16, 64));
                tw = fmaxf(tw, __shfl_xor(tw, 32, 64));
                float mn = fmaxf(m[t], tw);
                float scl = fexp2(m[t] - mn);
                m[t] = mn;
                l[t] *= scl;
                O[t][0] *= scl;
                O[t][1] *= scl;
            }

            float mt = m[t];
            float p[8][4];
            float lacc = 0.f;
            #pragma unroll
            for (int kk = 0; kk < 8; kk++) {
                p[kk][0] = fexp2(s[kk][0] - mt);
                p[kk][1] = fexp2(s[kk][1] - mt);
                p[kk][2] = fexp2(s[kk][2] - mt);
                p[kk][3] = fexp2(s[kk][3] - mt);
                lacc += (p[kk][0] + p[kk][1]) + (p[kk][2] + p[kk][3]);
            }
            l[t] += lacc;

            // P^T B-frags per 32-key block; slot order matches pi-permuted V chunks
            #pragma unroll
            for (int kk2 = 0; kk2 < 4; kk2++) {
                int c0 = __builtin_bit_cast(int, __builtin_amdgcn_cvt_pkrtz(p[2*kk2][0],   p[2*kk2][1]));
                int c1 = __builtin_bit_cast(int, __builtin_amdgcn_cvt_pkrtz(p[2*kk2][2],   p[2*kk2][3]));
                int c2 = __builtin_bit_cast(int, __builtin_amdgcn_cvt_pkrtz(p[2*kk2+1][0], p[2*kk2+1][1]));
                int c3 = __builtin_bit_cast(int, __builtin_amdgcn_cvt_pkrtz(p[2*kk2+1][2], p[2*kk2+1][3]));
                int4 pvi = {c0, c1, c2, c3};
                f16x8 pa = __builtin_bit_cast(f16x8, pvi);
                O[t][0] = __builtin_amdgcn_mfma_f32_16x16x32_f16(vf[0][kk2], pa, O[t][0], 0, 0, 0);
                O[t][1] = __builtin_amdgcn_mfma_f32_16x16x32_f16(vf[1][kk2], pa, O[t][1], 0, 0, 0);
            }
        }
    }

    // epilogue: reduce per-lane l, lane-local normalize + float4 stores
    float* obase = out + (size_t)(b * SEQ) * DIM + (g * HPG + w) * HD;
    #pragma unroll
    for (int t = 0; t < 2; t++) {
        float lt = l[t];
        lt += __shfl_xor(lt, 16, 64);
        lt += __shfl_xor(lt, 32, 64);
        float inv = 1.0f / lt;
        size_t rowoff = (size_t)(q0 + t * 16 + lr) * DIM;
        float4 o0 = {O[t][0][0] * inv, O[t][0][1] * inv, O[t][0][2] * inv, O[t][0][3] * inv};
        float4 o1 = {O[t][1][0] * inv, O[t][1][1] * inv, O[t][1][2] * inv, O[t][1][3] * inv};
        *reinterpret_cast<float4*>(obase + rowoff + lq * 4)      = o0;
        *reinterpret_cast<float4*>(obase + rowoff + 16 + lq * 4) = o1;
    }
    #undef STAGE
}

extern "C" void kernel_launch(void* const* d_in, const int* in_sizes, int n_in,
                              void* d_out, int out_size, void* d_ws, size_t ws_size,
                              hipStream_t stream) {
    const float* x  = (const float*)d_in[0];
    const float* wq = (const float*)d_in[1];
    const float* wk = (const float*)d_in[2];
    const float* wv = (const float*)d_in[3];
    float* out = (float*)d_out;

    unsigned short* ws  = (unsigned short*)d_ws;
    unsigned short* xb  = ws;                                  // 4096*1024
    unsigned short* wb  = xb + (size_t)BS * SEQ * DIM;         // 1536*1024
    unsigned short* qb  = wb + (size_t)NTOT * DIM;             // 4096*1024
    unsigned short* kb  = qb + (size_t)BS * SEQ * DIM;         // 4096*256
    unsigned short* vtb = kb + (size_t)BS * SEQ * KVD;         // 4096*256 (pi-transposed)

    cvt_x<<<1024, 256, 0, stream>>>(x, xb, BS * SEQ * DIM);
    cvt_w<<<1536, 256, 0, stream>>>(wq, wk, wv, wb);

    qkv_gemm<<<dim3(NTOT / 64, BS * SEQ / 128), 256, 0, stream>>>(xb, wb, qb, kb, vtb);
    gqa_attn<<<BS * G * (SEQ / 32), 256, 0, stream>>>(qb, kb, vtb, out);
}